// Round 3
// baseline (924.818 us; speedup 1.0000x reference)
//
#include <hip/hip_runtime.h>

#define BB 64
#define TT 1024
#define HH 1024
#define II 8
#define OO 8
#define RRK 4
#define NOISE_STD 0.05f
#define ALPHA 0.2f

typedef float v4f __attribute__((ext_vector_type(4)));
typedef float v2f __attribute__((ext_vector_type(2)));

// 2*log2(e): tanh argument scale so exp goes through native v_exp_f32 (2^x).
#define C2E 2.885390081777927f

// DPP-based add: acc + dpp_perm(src). VALU pipe (NOT ds_bpermute like __shfl).
template<int CTRL, int RM>
__device__ __forceinline__ float dpp_add(float acc, float src) {
    int s = __builtin_amdgcn_update_dpp(0, __float_as_int(src), CTRL, RM, 0xF, true);
    return acc + __int_as_float(s);
}

// Full wave64 sum; result valid on lane 63.
__device__ __forceinline__ float wave_sum(float x) {
    x = dpp_add<0xB1, 0xF>(x, x);   // xor 1
    x = dpp_add<0x4E, 0xF>(x, x);   // xor 2
    x = dpp_add<0x141, 0xF>(x, x);  // row_half_mirror
    x = dpp_add<0x140, 0xF>(x, x);  // row_mirror
    x = dpp_add<0x142, 0xA>(x, x);  // row_bcast:15
    x = dpp_add<0x143, 0xC>(x, x);  // row_bcast:31
    return x;
}

// tanh(x) = 1 - 2/(1 + 2^(2x*log2e)); argument passed as 2x*log2(e).
__device__ __forceinline__ float tanh_from_l2x(float l2x) {
    float e = __builtin_amdgcn_exp2f(l2x);
    float r = __builtin_amdgcn_rcpf(e + 1.0f);
    return fmaf(-2.0f, r, 1.0f);
}

// Barrier WITHOUT the vmcnt(0) drain of __syncthreads(): waits only LDS ops.
__device__ __forceinline__ void block_sync_lds() {
    asm volatile("s_waitcnt lgkmcnt(0)\n\ts_barrier" ::: "memory");
}

// ---------------------------------------------------------------------------
// Pre-kernel: W[row][o] = NOISE_STD * sum_h noise[row,h] * wo[h][o]*so[o]
// row = b*TT + t, 65536 rows. Double-buffered 8-row register tiles so global
// loads stay in flight UNDER the DPP compute (round-2 version had zero loads
// outstanding during compute -> Little's-law limited at 2.4 TB/s).
// ---------------------------------------------------------------------------
__global__ __launch_bounds__(256)
void prew_kernel(const float* __restrict__ noise, const float* __restrict__ wo,
                 const float* __restrict__ so, float* __restrict__ W) {
    __shared__ __align__(16) float red[2][8][4][8];   // ring x row x wave x o

    const int tid  = threadIdx.x;
    const int wave = tid >> 6;
    const int lane = tid & 63;
    const int e0   = tid << 2;                        // h = e0..e0+3

    float woa[4][OO];
    {
        float so8[OO];
        #pragma unroll
        for (int o = 0; o < OO; ++o) so8[o] = so[o] * NOISE_STD;
        #pragma unroll
        for (int e = 0; e < 4; ++e) {
            const float4 a4 = *(const float4*)(wo + (e0 + e) * OO);
            const float4 b4 = *(const float4*)(wo + (e0 + e) * OO + 4);
            woa[e][0] = a4.x * so8[0]; woa[e][1] = a4.y * so8[1];
            woa[e][2] = a4.z * so8[2]; woa[e][3] = a4.w * so8[3];
            woa[e][4] = b4.x * so8[4]; woa[e][5] = b4.y * so8[5];
            woa[e][6] = b4.z * so8[6]; woa[e][7] = b4.w * so8[7];
        }
    }

    const int row0 = blockIdx.x * 32;
    float4 nz[8], nzn[8];
    #pragma unroll
    for (int j = 0; j < 8; ++j)
        nz[j] = *(const float4*)(noise + (size_t)(row0 + j) * HH + e0);

    #pragma unroll
    for (int ph = 0; ph < 4; ++ph) {
        const int cur   = ph & 1;
        const int rbase = row0 + ph * 8;

        // prefetch next phase's 8 rows (in flight under this phase's DPP work)
        if (ph < 3) {
            #pragma unroll
            for (int j = 0; j < 8; ++j)
                nzn[j] = *(const float4*)(noise + (size_t)(rbase + 8 + j) * HH + e0);
        }

        #pragma unroll
        for (int j = 0; j < 8; ++j) {
            float op[OO];
            #pragma unroll
            for (int o = 0; o < OO; ++o)
                op[o] = fmaf(nz[j].x, woa[0][o], fmaf(nz[j].y, woa[1][o],
                        fmaf(nz[j].z, woa[2][o], nz[j].w * woa[3][o])));
            #pragma unroll
            for (int o = 0; o < OO; ++o) op[o] = wave_sum(op[o]);
            if (lane == 63) {
                *(float4*)&red[cur][j][wave][0] = make_float4(op[0], op[1], op[2], op[3]);
                *(float4*)&red[cur][j][wave][4] = make_float4(op[4], op[5], op[6], op[7]);
            }
        }
        block_sync_lds();
        if (tid < 64) {
            const int j = tid >> 3, o = tid & 7;
            W[(rbase + j) * OO + o] = (red[cur][j][0][o] + red[cur][j][1][o]) +
                                      (red[cur][j][2][o] + red[cur][j][3][o]);
        }
        // advance double buffer (register renames under full unroll)
        #pragma unroll
        for (int j = 0; j < 8; ++j) nz[j] = nzn[j];
        // no trailing barrier: next phase writes the OTHER ring slot; the
        // lgkmcnt(0) in the NEXT phase's barrier orders the tid<64 reads
        // before the phase-after-next reuses this slot.
    }
}

// ---------------------------------------------------------------------------
// Main RNN kernel: one block per batch, 512 threads = 8 waves, 2 hidden
// elems/lane (v2f -> v_pk_fma_f32). Rationale: with 256 threads each SIMD
// hosted exactly ONE wave, so every stall in the serial chain (6-deep DPP
// reduce, exp2->rcp tanh, LDS round-trip) was fully exposed (~937 cy/step vs
// ~264 cy of issue). Two waves/SIMD interleave independent streams and fill
// each other's stalls; per-wave instruction count barely grows (the DPP
// reduction is a fixed per-wave cost).
// ---------------------------------------------------------------------------
__global__ __launch_bounds__(512, 1)
void rnn_seq_kernel(const float* __restrict__ x, const float* __restrict__ noise,
                    const float* __restrict__ wi, const float* __restrict__ si,
                    const float* __restrict__ mM, const float* __restrict__ nM,
                    const float* __restrict__ bv, const float* __restrict__ wo,
                    const float* __restrict__ so, const float* __restrict__ h0,
                    const float* __restrict__ W, float* __restrict__ out) {
    __shared__ __align__(16) float lds_x[(TT + 1) * II]; // 32.03 KB (+1 pad row)
    __shared__ __align__(16) float lds_W[TT * OO];    // 32 KB (sigma-scaled noise@woa)
    __shared__ __align__(16) float lds_out[TT * OO];  // 32 KB
    __shared__ __align__(16) float red[4][8][4];      // ring x wave x q
    __shared__ __align__(16) float redc[8][104];      // preamble scratch (wave-major)
    __shared__ float ambx[104];                       // Am(32) | Bx(64) | y0(8)

    const int tid  = threadIdx.x;
    const int b    = blockIdx.x;
    const int wave = tid >> 6;
    const int lane = tid & 63;
    const int e0   = tid << 1;                        // 2 elems per lane
    const int oc   = tid & 7;                         // this thread's o-column for y

    // ---- stage x[b] and W[b] into LDS ----
    {
        const float4* sx = (const float4*)(x + (size_t)b * (TT * II));
        const float4* sw = (const float4*)(W + (size_t)b * (TT * OO));
        float4* dx = (float4*)lds_x;
        float4* dw = (float4*)lds_W;
        #pragma unroll
        for (int k = 0; k < 4; ++k) {
            dx[k * 512 + tid] = sx[k * 512 + tid];
            dw[k * 512 + tid] = sw[k * 512 + tid];
        }
        if (tid < 2) dx[2048 + tid] = sx[2046 + tid];  // pad row TT = row TT-1
    }

    // ---- fold constants into registers (per-lane: hidden elems e0, e0+1) ----
    v2f wiac[II];                                      // ALPHA*si[i]*wi[i][e0..e0+1]
    #pragma unroll
    for (int i = 0; i < II; ++i) {
        const float s  = ALPHA * si[i];
        const v2f w = *(const v2f*)(wi + i * HH + e0);
        wiac[i] = s * w;
    }
    v4f nr0, nr1;                                      // n rows e0,e0+1 (v4 over q)
    v4f ma0, ma1;                                      // cs-folded m rows (v4 over q)
    v2f mac[RRK];                                      // m column q (v2 over e)
    {
        const float cs = ALPHA / (float)HH;            // fold ALPHA/H into m
        ma0 = cs * *(const v4f*)(mM + (size_t)e0 * RRK);
        ma1 = cs * *(const v4f*)(mM + (size_t)(e0 + 1) * RRK);
        nr0 = *(const v4f*)(nM + (size_t)e0 * RRK);
        nr1 = *(const v4f*)(nM + (size_t)(e0 + 1) * RRK);
        mac[0] = (v2f){ma0.x, ma1.x};
        mac[1] = (v2f){ma0.y, ma1.y};
        mac[2] = (v2f){ma0.z, ma1.z};
        mac[3] = (v2f){ma0.w, ma1.w};
    }
    float woa[2][OO];                                  // wo[h_e][o]*so[o]  (preamble only)
    {
        #pragma unroll
        for (int e = 0; e < 2; ++e) {
            const float4 a4 = *(const float4*)(wo + (e0 + e) * OO);
            const float4 b4 = *(const float4*)(wo + (e0 + e) * OO + 4);
            woa[e][0] = a4.x * so[0]; woa[e][1] = a4.y * so[1];
            woa[e][2] = a4.z * so[2]; woa[e][3] = a4.w * so[3];
            woa[e][4] = b4.x * so[4]; woa[e][5] = b4.y * so[5];
            woa[e][6] = b4.z * so[6]; woa[e][7] = b4.w * so[7];
        }
    }
    v2f tb2e, h, r;
    {
        const v2f b2 = *(const v2f*)(bv + e0);
        tb2e = C2E * b2;                               // (2*log2e)*b
        h = *(const v2f*)(h0 + e0);
        v2f targ = C2E * h;
        r.x = tanh_from_l2x(targ.x);
        r.y = tanh_from_l2x(targ.y);
    }

    // ---- preamble: reduce Am (4x8), Bx (8x8), y0 (8) from register-folded weights ----
    // outputs k: [0,32) Am[q=k>>3][o=k&7]; [32,96) Bx[i=(k-32)>>3][o]; [96,104) y0[o]
    #pragma unroll
    for (int kg = 0; kg < 26; ++kg) {
        float p[4];
        #pragma unroll
        for (int u = 0; u < 4; ++u) {
            const int k = kg * 4 + u;
            float s;
            if (k < 32) {
                const int q = k >> 3, o = k & 7;
                const float m0 = (q == 0) ? ma0.x : (q == 1) ? ma0.y : (q == 2) ? ma0.z : ma0.w;
                const float m1 = (q == 0) ? ma1.x : (q == 1) ? ma1.y : (q == 2) ? ma1.z : ma1.w;
                s = fmaf(m0, woa[0][o], m1 * woa[1][o]);
            } else if (k < 96) {
                const int i = (k - 32) >> 3, o = k & 7;
                s = fmaf(wiac[i].x, woa[0][o], wiac[i].y * woa[1][o]);
            } else {
                const int o = k - 96;
                s = fmaf(h.x, woa[0][o], h.y * woa[1][o]);
            }
            p[u] = wave_sum(s);
        }
        if (lane == 63)
            *(float4*)&redc[wave][kg * 4] = make_float4(p[0], p[1], p[2], p[3]);
    }
    block_sync_lds();
    if (tid < 104)
        ambx[tid] = ((redc[0][tid] + redc[1][tid]) + (redc[2][tid] + redc[3][tid])) +
                    ((redc[4][tid] + redc[5][tid]) + (redc[6][tid] + redc[7][tid]));
    __syncthreads();   // also covers lds_x / lds_W staging visibility

    float Amr[RRK], Bxr[II], y;
    #pragma unroll
    for (int q = 0; q < RRK; ++q) Amr[q] = ambx[q * 8 + oc];
    #pragma unroll
    for (int i = 0; i < II; ++i) Bxr[i] = ambx[32 + i * 8 + oc];
    y = ambx[96 + oc];

    // ---- pipelined operand state for t=0 ----
    const float* nzp = noise + (size_t)b * (TT * HH) + e0;
    v2f nzb[4];
    #pragma unroll
    for (int j = 0; j < 4; ++j) nzb[j] = *(const v2f*)(nzp + j * HH);

    v4f xqc0 = *(const v4f*)&lds_x[0];
    v4f xqc1 = *(const v4f*)&lds_x[4];
    float wqc = lds_W[oc];

    for (int t0 = 0; t0 < TT; t0 += 4) {
        #pragma unroll
        for (int j = 0; j < 4; ++j) {
            const int t = t0 + j;

            // A. issue next-step operand loads early (pad row makes t+1 safe)
            const int tn = t + 1;
            const v4f xqn0 = *(const v4f*)&lds_x[tn * II];
            const v4f xqn1 = *(const v4f*)&lds_x[tn * II + 4];
            const float wqn = lds_W[(tn & (TT - 1)) * OO + oc];

            // B. v partials from r + in-wave reduction
            v4f vpv = r.x * nr0;
            vpv += r.y * nr1;
            float vp0 = wave_sum(vpv.x);
            float vp1 = wave_sum(vpv.y);
            float vp2 = wave_sum(vpv.z);
            float vp3 = wave_sum(vpv.w);
            if (lane == 63)
                *(float4*)&red[j][wave][0] = make_float4(vp0, vp1, vp2, vp3);

            // C. ybase = x_t·Bx[.][oc] + W_t[oc]  (v-independent part of y)
            float ybase = fmaf(xqc0.x, Bxr[0], wqc);
            ybase = fmaf(xqc0.y, Bxr[1], ybase);
            ybase = fmaf(xqc0.z, Bxr[2], ybase);
            ybase = fmaf(xqc0.w, Bxr[3], ybase);
            ybase = fmaf(xqc1.x, Bxr[4], ybase);
            ybase = fmaf(xqc1.y, Bxr[5], ybase);
            ybase = fmaf(xqc1.z, Bxr[6], ybase);
            ybase = fmaf(xqc1.w, Bxr[7], ybase);

            // D. alpha*u_t (packed FMA over the 2 hidden elems)
            v2f auv = xqc0.x * wiac[0];
            auv += xqc0.y * wiac[1];
            auv += xqc0.z * wiac[2];
            auv += xqc0.w * wiac[3];
            auv += xqc1.x * wiac[4];
            auv += xqc1.y * wiac[5];
            auv += xqc1.z * wiac[6];
            auv += xqc1.w * wiac[7];

            // E. LDS-only barrier (global prefetches stay in flight)
            block_sync_lds();

            // F. cross-wave v totals: 8 broadcast reads + tree add
            v4f vs;
            {
                const v4f s0 = *(const v4f*)&red[j][0][0];
                const v4f s1 = *(const v4f*)&red[j][1][0];
                const v4f s2 = *(const v4f*)&red[j][2][0];
                const v4f s3 = *(const v4f*)&red[j][3][0];
                const v4f s4 = *(const v4f*)&red[j][4][0];
                const v4f s5 = *(const v4f*)&red[j][5][0];
                const v4f s6 = *(const v4f*)&red[j][6][0];
                const v4f s7 = *(const v4f*)&red[j][7][0];
                vs = ((s0 + s1) + (s2 + s3)) + ((s4 + s5) + (s6 + s7));
            }

            // G. h update (packed FMA)
            v2f acc = auv;
            acc += vs.x * mac[0];
            acc += vs.y * mac[1];
            acc += vs.z * mac[2];
            acc += vs.w * mac[3];
            h = (1.0f - ALPHA) * h + acc;
            h += NOISE_STD * nzb[j];

            // H. y recurrence (all lanes compute column oc; tid<8 writes)
            {
                float t4 = fmaf(vs.x, Amr[0], ybase);
                t4 = fmaf(vs.y, Amr[1], t4);
                t4 = fmaf(vs.z, Amr[2], t4);
                t4 = fmaf(vs.w, Amr[3], t4);
                y = fmaf(1.0f - ALPHA, y, t4);
                if (tid < OO) lds_out[t * OO + tid] = y;
            }

            // I. noise prefetch for t+4 (wrap via mask; wrapped rows unused)
            nzb[j] = *(const v2f*)(nzp + ((t + 4) & (TT - 1)) * HH);

            // J. r = tanh(h + b) — critical path to next step (exp2-native)
            {
                v2f targ = C2E * h + tb2e;
                r.x = tanh_from_l2x(targ.x);
                r.y = tanh_from_l2x(targ.y);
            }

            // K. advance operand pipeline
            xqc0 = xqn0; xqc1 = xqn1; wqc = wqn;
        }
    }

    __syncthreads();
    {
        float4* dst = (float4*)(out + (size_t)b * (TT * OO));
        const float4* srcv = (const float4*)lds_out;
        #pragma unroll
        for (int k = 0; k < 4; ++k)
            dst[k * 512 + tid] = srcv[k * 512 + tid];
    }
}

extern "C" void kernel_launch(void* const* d_in, const int* in_sizes, int n_in,
                              void* d_out, int out_size, void* d_ws, size_t ws_size,
                              hipStream_t stream) {
    const float* x     = (const float*)d_in[0];
    const float* noise = (const float*)d_in[1];
    const float* wi    = (const float*)d_in[2];
    const float* si    = (const float*)d_in[3];
    const float* mM    = (const float*)d_in[4];
    const float* nM    = (const float*)d_in[5];
    const float* bv    = (const float*)d_in[6];
    const float* wo    = (const float*)d_in[7];
    const float* so    = (const float*)d_in[8];
    const float* h0    = (const float*)d_in[9];
    float* out = (float*)d_out;
    float* W   = (float*)d_ws;   // 65536 x 8 fp32 = 2 MB

    prew_kernel<<<dim3(2048), dim3(256), 0, stream>>>(noise, wo, so, W);
    rnn_seq_kernel<<<dim3(BB), dim3(512), 0, stream>>>(
        x, noise, wi, si, mM, nM, bv, wo, so, h0, W, out);
}

// Round 4
// 864.593 us; speedup vs baseline: 1.0697x; 1.0697x over previous
//
#include <hip/hip_runtime.h>

#define BB 64
#define TT 1024
#define HH 1024
#define II 8
#define OO 8
#define RRK 4
#define NOISE_STD 0.05f
#define ALPHA 0.2f

typedef float v4f __attribute__((ext_vector_type(4)));

// 2*log2(e): tanh argument scale so exp goes through native v_exp_f32 (2^x).
#define C2E 2.885390081777927f

// DPP-based add: acc + dpp_perm(src). VALU pipe (NOT ds_bpermute like __shfl).
template<int CTRL, int RM>
__device__ __forceinline__ float dpp_add(float acc, float src) {
    int s = __builtin_amdgcn_update_dpp(0, __float_as_int(src), CTRL, RM, 0xF, true);
    return acc + __int_as_float(s);
}

// Full wave64 sum; result valid on lane 63.
__device__ __forceinline__ float wave_sum(float x) {
    x = dpp_add<0xB1, 0xF>(x, x);   // xor 1
    x = dpp_add<0x4E, 0xF>(x, x);   // xor 2
    x = dpp_add<0x141, 0xF>(x, x);  // row_half_mirror
    x = dpp_add<0x140, 0xF>(x, x);  // row_mirror
    x = dpp_add<0x142, 0xA>(x, x);  // row_bcast:15
    x = dpp_add<0x143, 0xC>(x, x);  // row_bcast:31
    return x;
}

// tanh(x) = 1 - 2/(1 + 2^(2x*log2e)); argument passed as 2x*log2(e).
__device__ __forceinline__ float tanh_from_l2x(float l2x) {
    float e = __builtin_amdgcn_exp2f(l2x);
    float r = __builtin_amdgcn_rcpf(e + 1.0f);
    return fmaf(-2.0f, r, 1.0f);
}

// Barrier WITHOUT the vmcnt(0) drain of __syncthreads(): waits only LDS ops.
__device__ __forceinline__ void block_sync_lds() {
    asm volatile("s_waitcnt lgkmcnt(0)\n\ts_barrier" ::: "memory");
}

// ---------------------------------------------------------------------------
// Pre-kernel: W[row][o] = NOISE_STD * sum_h noise[row,h] * wo[h][o]*so[o]
// (unchanged from round 3)
// ---------------------------------------------------------------------------
__global__ __launch_bounds__(256)
void prew_kernel(const float* __restrict__ noise, const float* __restrict__ wo,
                 const float* __restrict__ so, float* __restrict__ W) {
    __shared__ __align__(16) float red[2][8][4][8];   // ring x row x wave x o

    const int tid  = threadIdx.x;
    const int wave = tid >> 6;
    const int lane = tid & 63;
    const int e0   = tid << 2;                        // h = e0..e0+3

    float woa[4][OO];
    {
        float so8[OO];
        #pragma unroll
        for (int o = 0; o < OO; ++o) so8[o] = so[o] * NOISE_STD;
        #pragma unroll
        for (int e = 0; e < 4; ++e) {
            const float4 a4 = *(const float4*)(wo + (e0 + e) * OO);
            const float4 b4 = *(const float4*)(wo + (e0 + e) * OO + 4);
            woa[e][0] = a4.x * so8[0]; woa[e][1] = a4.y * so8[1];
            woa[e][2] = a4.z * so8[2]; woa[e][3] = a4.w * so8[3];
            woa[e][4] = b4.x * so8[4]; woa[e][5] = b4.y * so8[5];
            woa[e][6] = b4.z * so8[6]; woa[e][7] = b4.w * so8[7];
        }
    }

    const int row0 = blockIdx.x * 32;
    float4 nz[8], nzn[8];
    #pragma unroll
    for (int j = 0; j < 8; ++j)
        nz[j] = *(const float4*)(noise + (size_t)(row0 + j) * HH + e0);

    #pragma unroll
    for (int ph = 0; ph < 4; ++ph) {
        const int cur   = ph & 1;
        const int rbase = row0 + ph * 8;

        if (ph < 3) {
            #pragma unroll
            for (int j = 0; j < 8; ++j)
                nzn[j] = *(const float4*)(noise + (size_t)(rbase + 8 + j) * HH + e0);
        }

        #pragma unroll
        for (int j = 0; j < 8; ++j) {
            float op[OO];
            #pragma unroll
            for (int o = 0; o < OO; ++o)
                op[o] = fmaf(nz[j].x, woa[0][o], fmaf(nz[j].y, woa[1][o],
                        fmaf(nz[j].z, woa[2][o], nz[j].w * woa[3][o])));
            #pragma unroll
            for (int o = 0; o < OO; ++o) op[o] = wave_sum(op[o]);
            if (lane == 63) {
                *(float4*)&red[cur][j][wave][0] = make_float4(op[0], op[1], op[2], op[3]);
                *(float4*)&red[cur][j][wave][4] = make_float4(op[4], op[5], op[6], op[7]);
            }
        }
        block_sync_lds();
        if (tid < 64) {
            const int j = tid >> 3, o = tid & 7;
            W[(rbase + j) * OO + o] = (red[cur][j][0][o] + red[cur][j][1][o]) +
                                      (red[cur][j][2][o] + red[cur][j][3][o]);
        }
        #pragma unroll
        for (int j = 0; j < 8; ++j) nz[j] = nzn[j];
    }
}

// ---------------------------------------------------------------------------
// Main RNN kernel: one block per batch, 128 threads = 2 waves, 8 hidden
// elems/lane. Lesson from r1/r3: step time = per-SIMD issue + exposed chain,
// and both scale with wave count through fixed per-wave costs (the 24-op DPP
// reduce, barrier machinery). So: FEWER waves, MORE elems/lane, and the
// y-recurrence moved OUT of the loop (constant-coefficient linear recurrence
// -> exact chunked scan post-pass; only v_t (4 floats) is logged per step).
// ---------------------------------------------------------------------------
__global__ __launch_bounds__(128, 1)
void rnn_seq_kernel(const float* __restrict__ x, const float* __restrict__ noise,
                    const float* __restrict__ wi, const float* __restrict__ si,
                    const float* __restrict__ mM, const float* __restrict__ nM,
                    const float* __restrict__ bv, const float* __restrict__ wo,
                    const float* __restrict__ so, const float* __restrict__ h0,
                    const float* __restrict__ W, float* __restrict__ out) {
    __shared__ __align__(16) float lds_x[(TT + 1) * II];  // 32.03 KB (+1 pad row)
    __shared__ __align__(16) float lds_v[TT * RRK];       // 16 KB (v_t history)
    __shared__ __align__(16) float lds_out[TT * OO];      // 32 KB
    __shared__ __align__(16) float red[4][2][4];          // ring x wave x q
    __shared__ __align__(16) float redc[2][104];          // preamble scratch
    __shared__ float ambx[104];                           // Am(32) | Bx(64) | y0(8)
    __shared__ float chs[16][OO];                         // post-pass chunk scan

    const int tid  = threadIdx.x;
    const int b    = blockIdx.x;
    const int wave = tid >> 6;
    const int lane = tid & 63;
    const int e0   = tid << 3;                            // 8 elems per lane
    const int oc   = tid & 7;

    // ---- stage x[b] into LDS ----
    {
        const float4* sx = (const float4*)(x + (size_t)b * (TT * II));
        float4* dx = (float4*)lds_x;
        #pragma unroll
        for (int k = 0; k < 16; ++k)
            dx[k * 128 + tid] = sx[k * 128 + tid];
        if (tid < 2) dx[2048 + tid] = sx[2046 + tid];     // pad row TT = row TT-1
    }

    // ---- fold constants into registers (elems e0..e0+7) ----
    v4f wiaA[II], wiaB[II];                               // ALPHA*si[i]*wi[i][e]
    #pragma unroll
    for (int i = 0; i < II; ++i) {
        const float s = ALPHA * si[i];
        wiaA[i] = s * *(const v4f*)(wi + (size_t)i * HH + e0);
        wiaB[i] = s * *(const v4f*)(wi + (size_t)i * HH + e0 + 4);
    }
    v4f nrv[8];                                           // n rows (v4 over q)
    #pragma unroll
    for (int e = 0; e < 8; ++e)
        nrv[e] = *(const v4f*)(nM + (size_t)(e0 + e) * RRK);
    v4f maA[RRK], maB[RRK];                               // cs-folded m columns (v4 over e)
    {
        const float cs = ALPHA / (float)HH;
        v4f mrow[8];
        #pragma unroll
        for (int e = 0; e < 8; ++e)
            mrow[e] = cs * *(const v4f*)(mM + (size_t)(e0 + e) * RRK);
        #pragma unroll
        for (int q = 0; q < RRK; ++q) {
            maA[q] = (v4f){mrow[0][q], mrow[1][q], mrow[2][q], mrow[3][q]};
            maB[q] = (v4f){mrow[4][q], mrow[5][q], mrow[6][q], mrow[7][q]};
        }
    }
    float woa[8][OO];                                     // wo[e][o]*so[o] (preamble only)
    #pragma unroll
    for (int e = 0; e < 8; ++e) {
        const float4 a4 = *(const float4*)(wo + (size_t)(e0 + e) * OO);
        const float4 b4 = *(const float4*)(wo + (size_t)(e0 + e) * OO + 4);
        woa[e][0] = a4.x * so[0]; woa[e][1] = a4.y * so[1];
        woa[e][2] = a4.z * so[2]; woa[e][3] = a4.w * so[3];
        woa[e][4] = b4.x * so[4]; woa[e][5] = b4.y * so[5];
        woa[e][6] = b4.z * so[6]; woa[e][7] = b4.w * so[7];
    }
    v4f tbA, tbB, hA, hB, rA, rB;
    {
        tbA = C2E * *(const v4f*)(bv + e0);
        tbB = C2E * *(const v4f*)(bv + e0 + 4);
        hA = *(const v4f*)(h0 + e0);
        hB = *(const v4f*)(h0 + e0 + 4);
        const v4f ta = C2E * hA, tb = C2E * hB;
        rA.x = tanh_from_l2x(ta.x); rA.y = tanh_from_l2x(ta.y);
        rA.z = tanh_from_l2x(ta.z); rA.w = tanh_from_l2x(ta.w);
        rB.x = tanh_from_l2x(tb.x); rB.y = tanh_from_l2x(tb.y);
        rB.z = tanh_from_l2x(tb.z); rB.w = tanh_from_l2x(tb.w);
    }

    // ---- preamble: reduce Am (4x8), Bx (8x8), y0 (8) ----
    // outputs k: [0,32) Am[q=k>>3][o=k&7]; [32,96) Bx[i=(k-32)>>3][o]; [96,104) y0[o]
    #pragma unroll
    for (int kg = 0; kg < 26; ++kg) {
        float p[4];
        #pragma unroll
        for (int u = 0; u < 4; ++u) {
            const int k = kg * 4 + u;
            float s;
            if (k < 32) {
                const int q = k >> 3, o = k & 7;
                s = maA[q].x * woa[0][o];
                s = fmaf(maA[q].y, woa[1][o], s);
                s = fmaf(maA[q].z, woa[2][o], s);
                s = fmaf(maA[q].w, woa[3][o], s);
                s = fmaf(maB[q].x, woa[4][o], s);
                s = fmaf(maB[q].y, woa[5][o], s);
                s = fmaf(maB[q].z, woa[6][o], s);
                s = fmaf(maB[q].w, woa[7][o], s);
            } else if (k < 96) {
                const int i = (k - 32) >> 3, o = k & 7;
                s = wiaA[i].x * woa[0][o];
                s = fmaf(wiaA[i].y, woa[1][o], s);
                s = fmaf(wiaA[i].z, woa[2][o], s);
                s = fmaf(wiaA[i].w, woa[3][o], s);
                s = fmaf(wiaB[i].x, woa[4][o], s);
                s = fmaf(wiaB[i].y, woa[5][o], s);
                s = fmaf(wiaB[i].z, woa[6][o], s);
                s = fmaf(wiaB[i].w, woa[7][o], s);
            } else {
                const int o = k - 96;
                s = hA.x * woa[0][o];
                s = fmaf(hA.y, woa[1][o], s);
                s = fmaf(hA.z, woa[2][o], s);
                s = fmaf(hA.w, woa[3][o], s);
                s = fmaf(hB.x, woa[4][o], s);
                s = fmaf(hB.y, woa[5][o], s);
                s = fmaf(hB.z, woa[6][o], s);
                s = fmaf(hB.w, woa[7][o], s);
            }
            p[u] = wave_sum(s);
        }
        if (lane == 63)
            *(float4*)&redc[wave][kg * 4] = make_float4(p[0], p[1], p[2], p[3]);
    }
    block_sync_lds();
    if (tid < 104)
        ambx[tid] = redc[0][tid] + redc[1][tid];
    __syncthreads();   // also covers lds_x staging visibility

    // ---- pipelined operand state for t=0 ----
    const float* nzp0 = noise + (size_t)b * (TT * HH) + e0;
    v4f nzA[4], nzB[4];
    #pragma unroll
    for (int j = 0; j < 4; ++j) {
        nzA[j] = *(const v4f*)(nzp0 + (size_t)j * HH);
        nzB[j] = *(const v4f*)(nzp0 + (size_t)j * HH + 4);
    }
    const float* nzq = nzp0 + (size_t)4 * HH;

    v4f xc0 = *(const v4f*)&lds_x[0];
    v4f xc1 = *(const v4f*)&lds_x[4];

#define RNN_STEP(t, j, PF)                                                     \
    {                                                                          \
        const v4f xn0 = *(const v4f*)&lds_x[((t) + 1) * II];                   \
        const v4f xn1 = *(const v4f*)&lds_x[((t) + 1) * II + 4];               \
        v4f vpa = rA.x * nrv[0];                                               \
        v4f vpb = rB.x * nrv[4];                                               \
        vpa += rA.y * nrv[1]; vpb += rB.y * nrv[5];                            \
        vpa += rA.z * nrv[2]; vpb += rB.z * nrv[6];                            \
        vpa += rA.w * nrv[3]; vpb += rB.w * nrv[7];                            \
        const v4f vp = vpa + vpb;                                              \
        const float vp0 = wave_sum(vp.x); const float vp1 = wave_sum(vp.y);    \
        const float vp2 = wave_sum(vp.z); const float vp3 = wave_sum(vp.w);    \
        if (lane == 63)                                                        \
            *(float4*)&red[j][wave][0] = make_float4(vp0, vp1, vp2, vp3);      \
        v4f auA = xc0.x * wiaA[0], auB = xc0.x * wiaB[0];                      \
        auA += xc0.y * wiaA[1]; auB += xc0.y * wiaB[1];                        \
        auA += xc0.z * wiaA[2]; auB += xc0.z * wiaB[2];                        \
        auA += xc0.w * wiaA[3]; auB += xc0.w * wiaB[3];                        \
        auA += xc1.x * wiaA[4]; auB += xc1.x * wiaB[4];                        \
        auA += xc1.y * wiaA[5]; auB += xc1.y * wiaB[5];                        \
        auA += xc1.z * wiaA[6]; auB += xc1.z * wiaB[6];                        \
        auA += xc1.w * wiaA[7]; auB += xc1.w * wiaB[7];                        \
        block_sync_lds();                                                      \
        const v4f vs = *(const v4f*)&red[j][0][0] + *(const v4f*)&red[j][1][0];\
        if (tid == 0) *(v4f*)&lds_v[(t) * RRK] = vs;                           \
        v4f accA = auA + vs.x * maA[0], accB = auB + vs.x * maB[0];            \
        accA += vs.y * maA[1]; accB += vs.y * maB[1];                          \
        accA += vs.z * maA[2]; accB += vs.z * maB[2];                          \
        accA += vs.w * maA[3]; accB += vs.w * maB[3];                          \
        hA = (1.0f - ALPHA) * hA + accA;  hA += NOISE_STD * nzA[j];            \
        hB = (1.0f - ALPHA) * hB + accB;  hB += NOISE_STD * nzB[j];            \
        if (PF) {                                                              \
            nzA[j] = *(const v4f*)nzq;                                         \
            nzB[j] = *(const v4f*)(nzq + 4);                                   \
            nzq += HH;                                                         \
        }                                                                      \
        const v4f tgA = C2E * hA + tbA, tgB = C2E * hB + tbB;                  \
        rA.x = tanh_from_l2x(tgA.x); rA.y = tanh_from_l2x(tgA.y);              \
        rA.z = tanh_from_l2x(tgA.z); rA.w = tanh_from_l2x(tgA.w);              \
        rB.x = tanh_from_l2x(tgB.x); rB.y = tanh_from_l2x(tgB.y);              \
        rB.z = tanh_from_l2x(tgB.z); rB.w = tanh_from_l2x(tgB.w);              \
        xc0 = xn0; xc1 = xn1;                                                  \
    }

    for (int t0 = 0; t0 < TT - 4; t0 += 4) {
        RNN_STEP(t0 + 0, 0, 1)
        RNN_STEP(t0 + 1, 1, 1)
        RNN_STEP(t0 + 2, 2, 1)
        RNN_STEP(t0 + 3, 3, 1)
    }
    // peeled tail: no prefetch -> no wrap logic in the hot loop
    RNN_STEP(TT - 4, 0, 0)
    RNN_STEP(TT - 3, 1, 0)
    RNN_STEP(TT - 2, 2, 0)
    RNN_STEP(TT - 1, 3, 0)
#undef RNN_STEP

    // ---- post-pass: y_t = 0.8*y_{t-1} + (x_t.Bx + W_t + v_t.Am), exact
    // chunked scan. thread = (chunk c = tid>>3, col o = tid&7), 64 t/chunk.
    __syncthreads();

    float Bxr[II], Amr[RRK];
    #pragma unroll
    for (int q = 0; q < RRK; ++q) Amr[q] = ambx[q * 8 + oc];
    #pragma unroll
    for (int i = 0; i < II; ++i) Bxr[i] = ambx[32 + i * 8 + oc];
    const float y0v = ambx[96 + oc];

    const int c   = tid >> 3;
    const int t0c = c * 64;
    float a64;
    {
        float a = 1.0f - ALPHA;
        a = a * a; a = a * a; a = a * a;      // ^8
        a = a * a; a = a * a; a = a * a;      // ^64
        a64 = a;
    }
    const float* Wb = W + (size_t)b * (TT * OO);
    float st[64];
    float L = 0.0f;
    #pragma unroll
    for (int jt = 0; jt < 64; ++jt) {
        const int t = t0c + jt;
        const v4f xa = *(const v4f*)&lds_x[t * II];
        const v4f xb = *(const v4f*)&lds_x[t * II + 4];
        const v4f vv = *(const v4f*)&lds_v[t * RRK];
        float s = Wb[t * OO + oc];
        s = fmaf(xa.x, Bxr[0], s); s = fmaf(xa.y, Bxr[1], s);
        s = fmaf(xa.z, Bxr[2], s); s = fmaf(xa.w, Bxr[3], s);
        s = fmaf(xb.x, Bxr[4], s); s = fmaf(xb.y, Bxr[5], s);
        s = fmaf(xb.z, Bxr[6], s); s = fmaf(xb.w, Bxr[7], s);
        s = fmaf(vv.x, Amr[0], s); s = fmaf(vv.y, Amr[1], s);
        s = fmaf(vv.z, Amr[2], s); s = fmaf(vv.w, Amr[3], s);
        st[jt] = s;
        L = fmaf(1.0f - ALPHA, L, s);
    }
    chs[c][oc] = L;
    block_sync_lds();
    if (tid < OO) {                       // one scanner per column (exact carry)
        float Y = ambx[96 + tid];         // y_{-1}
        #pragma unroll
        for (int c2 = 0; c2 < 16; ++c2) {
            const float Lc = chs[c2][tid];
            chs[c2][tid] = Y;             // carry-in for chunk c2
            Y = fmaf(a64, Y, Lc);
        }
    }
    block_sync_lds();
    float yv = chs[c][oc];
    (void)y0v;
    #pragma unroll
    for (int jt = 0; jt < 64; ++jt) {
        yv = fmaf(1.0f - ALPHA, yv, st[jt]);
        lds_out[(t0c + jt) * OO + oc] = yv;
    }
    __syncthreads();
    {
        float4* dst = (float4*)(out + (size_t)b * (TT * OO));
        const float4* srcv = (const float4*)lds_out;
        #pragma unroll
        for (int k = 0; k < 16; ++k)
            dst[k * 128 + tid] = srcv[k * 128 + tid];
    }
}

extern "C" void kernel_launch(void* const* d_in, const int* in_sizes, int n_in,
                              void* d_out, int out_size, void* d_ws, size_t ws_size,
                              hipStream_t stream) {
    const float* x     = (const float*)d_in[0];
    const float* noise = (const float*)d_in[1];
    const float* wi    = (const float*)d_in[2];
    const float* si    = (const float*)d_in[3];
    const float* mM    = (const float*)d_in[4];
    const float* nM    = (const float*)d_in[5];
    const float* bv    = (const float*)d_in[6];
    const float* wo    = (const float*)d_in[7];
    const float* so    = (const float*)d_in[8];
    const float* h0    = (const float*)d_in[9];
    float* out = (float*)d_out;
    float* W   = (float*)d_ws;   // 65536 x 8 fp32 = 2 MB

    prew_kernel<<<dim3(2048), dim3(256), 0, stream>>>(noise, wo, so, W);
    rnn_seq_kernel<<<dim3(BB), dim3(128), 0, stream>>>(
        x, noise, wi, si, mM, nM, bv, wo, so, h0, W, out);
}